// Round 1
// baseline (3457.568 us; speedup 1.0000x reference)
//
#include <hip/hip_runtime.h>

#define N_NODES 50000
#define N_EDGES 800000
#define E_TOT   850000           // edges + self loops
#define IN_DIM  128
#define HID     64
#define HEADS   4
#define C1      256              // HEADS*HID
#define OUT_DIM 64
#define NEG_SLOPE 0.2f

// ---------------------------------------------------------------------------
// GEMM1: h1 = x @ W1  [50000x128]@[128x256], plus fused per-head attention
// projections as1/ad1 (wave w == head w since HID==64).
// Block: 256 threads (thread t = output column t), 16 nodes per block.
// x tile staged in LDS (broadcast reads); W1 streamed through L2.
// ---------------------------------------------------------------------------
__global__ __launch_bounds__(256) void gemm1_kernel(
    const float* __restrict__ x, const float* __restrict__ W1,
    const float* __restrict__ a_src1, const float* __restrict__ a_dst1,
    float* __restrict__ h1, float* __restrict__ as1, float* __restrict__ ad1)
{
    __shared__ float xs[16][IN_DIM];           // 8 KiB
    const int t = threadIdx.x;
    const int nodeBase = blockIdx.x * 16;      // N_NODES % 16 == 0

    {   // stage 16x128 x-tile: 8 floats per thread, fully coalesced
        const float* src = x + (size_t)nodeBase * IN_DIM;
        float4 v0 = *(const float4*)(src + t * 8);
        float4 v1 = *(const float4*)(src + t * 8 + 4);
        int n = (t * 8) / IN_DIM, k = (t * 8) % IN_DIM;
        *(float4*)&xs[n][k]     = v0;
        *(float4*)&xs[n][k + 4] = v1;
    }
    __syncthreads();

    float acc[16];
    #pragma unroll
    for (int n = 0; n < 16; n++) acc[n] = 0.f;

    for (int k = 0; k < IN_DIM; k += 4) {
        float w0 = W1[(k + 0) * C1 + t];
        float w1 = W1[(k + 1) * C1 + t];
        float w2 = W1[(k + 2) * C1 + t];
        float w3 = W1[(k + 3) * C1 + t];
        #pragma unroll
        for (int n = 0; n < 16; n++) {
            float4 xv = *(const float4*)&xs[n][k];   // LDS broadcast
            acc[n] = fmaf(xv.x, w0, acc[n]);
            acc[n] = fmaf(xv.y, w1, acc[n]);
            acc[n] = fmaf(xv.z, w2, acc[n]);
            acc[n] = fmaf(xv.w, w3, acc[n]);
        }
    }

    #pragma unroll
    for (int n = 0; n < 16; n++)
        h1[(size_t)(nodeBase + n) * C1 + t] = acc[n];

    // attention projections: channel t = head*64 + lane, so a_src1 flat-index == t
    const int lane = t & 63;
    const int head = t >> 6;
    const float asw = a_src1[t];
    const float adw = a_dst1[t];
    #pragma unroll
    for (int n = 0; n < 16; n++) {
        float s = acc[n] * asw;
        float d = acc[n] * adw;
        #pragma unroll
        for (int off = 32; off; off >>= 1) {
            s += __shfl_down(s, off, 64);
            d += __shfl_down(d, off, 64);
        }
        if (lane == 0) {
            as1[(nodeBase + n) * HEADS + head] = s;
            ad1[(nodeBase + n) * HEADS + head] = d;
        }
    }
}

// ---------------------------------------------------------------------------
// Edge pass 1: e = leakyrelu(as[src]+ad[dst]); w = exp(e) (no max-subtraction:
// mathematically identical softmax, |e| <~ 8 so no overflow). Store w, and
// accumulate denominator per (dst, head).
// ---------------------------------------------------------------------------
template <int H>
__global__ void edge_pass1_kernel(
    const int* __restrict__ src_a, const int* __restrict__ dst_a,
    const float* __restrict__ as, const float* __restrict__ ad,
    float* __restrict__ wbuf, float* __restrict__ den)
{
    int j = blockIdx.x * blockDim.x + threadIdx.x;
    if (j >= E_TOT) return;
    int s, d;
    if (j < N_EDGES) { s = src_a[j]; d = dst_a[j]; }
    else             { s = j - N_EDGES; d = s; }        // self loop
    #pragma unroll
    for (int h = 0; h < H; h++) {
        float e = as[s * H + h] + ad[d * H + h];
        e = e > 0.f ? e : NEG_SLOPE * e;
        float w = __expf(e);
        wbuf[j * H + h] = w;
        atomicAdd(&den[d * H + h], w);
    }
}

// ---------------------------------------------------------------------------
// Edge pass 2 (layer 1): one wave per edge; lane covers 4 channels (float4).
// head = (4*lane)/64 = lane>>4. Scatter alpha * h1[src] into out1agg[dst].
// ---------------------------------------------------------------------------
__global__ void edge_pass2_l1_kernel(
    const int* __restrict__ src_a, const int* __restrict__ dst_a,
    const float* __restrict__ h1, const float* __restrict__ wbuf,
    const float* __restrict__ den, float* __restrict__ outagg)
{
    long long gid = (long long)blockIdx.x * blockDim.x + threadIdx.x;
    int j = (int)(gid >> 6);
    int lane = threadIdx.x & 63;
    if (j >= E_TOT) return;
    int s, d;
    if (j < N_EDGES) { s = src_a[j]; d = dst_a[j]; }
    else             { s = j - N_EDGES; d = s; }
    int h = lane >> 4;
    float alpha = wbuf[j * 4 + h] / (den[d * 4 + h] + 1e-16f);
    float4 hv = *(const float4*)(h1 + (size_t)s * C1 + lane * 4);
    float* o = outagg + (size_t)d * C1 + lane * 4;
    atomicAdd(o + 0, alpha * hv.x);
    atomicAdd(o + 1, alpha * hv.y);
    atomicAdd(o + 2, alpha * hv.z);
    atomicAdd(o + 3, alpha * hv.w);
}

// ---------------------------------------------------------------------------
// GEMM2: h2 = ELU(out1agg + b1) @ W2  [50000x256]@[256x64] + fused as2/ad2.
// Block: 256 threads = 4 waves; wave `sub` owns 4 nodes, thread col c=t&63.
// Activated input tile staged in LDS.
// ---------------------------------------------------------------------------
__global__ __launch_bounds__(256) void gemm2_kernel(
    const float* __restrict__ in_agg, const float* __restrict__ b1,
    const float* __restrict__ W2, const float* __restrict__ a_src2,
    const float* __restrict__ a_dst2,
    float* __restrict__ h2, float* __restrict__ as2, float* __restrict__ ad2)
{
    __shared__ float xs[16][C1];               // 16 KiB
    const int t = threadIdx.x;
    const int nodeBase = blockIdx.x * 16;

    {   // stage 16x256 tile with bias + ELU fused (16 floats per thread)
        const float* src = in_agg + (size_t)nodeBase * C1;
        #pragma unroll
        for (int i = 0; i < 4; i++) {
            int idx = t * 16 + i * 4;
            int n = idx / C1, c = idx % C1;
            float4 v  = *(const float4*)(src + idx);
            float4 bb = *(const float4*)(b1 + c);
            v.x += bb.x; v.y += bb.y; v.z += bb.z; v.w += bb.w;
            v.x = v.x > 0.f ? v.x : __expf(v.x) - 1.f;
            v.y = v.y > 0.f ? v.y : __expf(v.y) - 1.f;
            v.z = v.z > 0.f ? v.z : __expf(v.z) - 1.f;
            v.w = v.w > 0.f ? v.w : __expf(v.w) - 1.f;
            *(float4*)&xs[n][c] = v;
        }
    }
    __syncthreads();

    const int c = t & 63;
    const int sub = t >> 6;
    float acc[4];
    #pragma unroll
    for (int i = 0; i < 4; i++) acc[i] = 0.f;

    for (int k = 0; k < C1; k += 4) {
        float w0 = W2[(k + 0) * OUT_DIM + c];
        float w1 = W2[(k + 1) * OUT_DIM + c];
        float w2v = W2[(k + 2) * OUT_DIM + c];
        float w3 = W2[(k + 3) * OUT_DIM + c];
        #pragma unroll
        for (int i = 0; i < 4; i++) {
            float4 xv = *(const float4*)&xs[sub * 4 + i][k];
            acc[i] = fmaf(xv.x, w0, acc[i]);
            acc[i] = fmaf(xv.y, w1, acc[i]);
            acc[i] = fmaf(xv.z, w2v, acc[i]);
            acc[i] = fmaf(xv.w, w3, acc[i]);
        }
    }

    const float asw = a_src2[c];
    const float adw = a_dst2[c];
    #pragma unroll
    for (int i = 0; i < 4; i++) {
        int node = nodeBase + sub * 4 + i;
        h2[(size_t)node * OUT_DIM + c] = acc[i];
        float s = acc[i] * asw;
        float dd = acc[i] * adw;
        #pragma unroll
        for (int off = 32; off; off >>= 1) {
            s  += __shfl_down(s, off, 64);
            dd += __shfl_down(dd, off, 64);
        }
        if (c == 0) { as2[node] = s; ad2[node] = dd; }
    }
}

// ---------------------------------------------------------------------------
// Edge pass 2 (layer 2): one wave per edge, lane = channel (OUT_DIM=64).
// ---------------------------------------------------------------------------
__global__ void edge_pass2_l2_kernel(
    const int* __restrict__ src_a, const int* __restrict__ dst_a,
    const float* __restrict__ h2, const float* __restrict__ wbuf,
    const float* __restrict__ den, float* __restrict__ outagg)
{
    long long gid = (long long)blockIdx.x * blockDim.x + threadIdx.x;
    int j = (int)(gid >> 6);
    int lane = threadIdx.x & 63;
    if (j >= E_TOT) return;
    int s, d;
    if (j < N_EDGES) { s = src_a[j]; d = dst_a[j]; }
    else             { s = j - N_EDGES; d = s; }
    float alpha = wbuf[j] / (den[d] + 1e-16f);
    atomicAdd(outagg + (size_t)d * OUT_DIM + lane, alpha * h2[(size_t)s * OUT_DIM + lane]);
}

// ---------------------------------------------------------------------------
// Final: out[n] = dot(out2agg[n] + b2, fc_w) + fc_b.  One wave per node.
// ---------------------------------------------------------------------------
__global__ void final_kernel(
    const float* __restrict__ outagg, const float* __restrict__ b2,
    const float* __restrict__ fc_w, const float* __restrict__ fc_b,
    float* __restrict__ out)
{
    int gid = blockIdx.x * blockDim.x + threadIdx.x;
    int node = gid >> 6;
    int lane = threadIdx.x & 63;
    if (node >= N_NODES) return;
    float v = outagg[(size_t)node * OUT_DIM + lane] + b2[lane];
    float acc = v * fc_w[lane];
    #pragma unroll
    for (int off = 32; off; off >>= 1) acc += __shfl_down(acc, off, 64);
    if (lane == 0) out[node] = acc + fc_b[0];
}

extern "C" void kernel_launch(void* const* d_in, const int* in_sizes, int n_in,
                              void* d_out, int out_size, void* d_ws, size_t ws_size,
                              hipStream_t stream)
{
    const float* x      = (const float*)d_in[0];
    const int*   ei     = (const int*)d_in[1];     // int32 (JAX x64 disabled)
    const float* W1     = (const float*)d_in[2];
    const float* a_src1 = (const float*)d_in[3];
    const float* a_dst1 = (const float*)d_in[4];
    const float* b1     = (const float*)d_in[5];
    const float* W2     = (const float*)d_in[6];
    const float* a_src2 = (const float*)d_in[7];
    const float* a_dst2 = (const float*)d_in[8];
    const float* b2     = (const float*)d_in[9];
    const float* fc_w   = (const float*)d_in[10];
    const float* fc_b   = (const float*)d_in[11];
    float* out = (float*)d_out;

    const int* srcA = ei;
    const int* dstA = ei + N_EDGES;

    // workspace layout (floats); zeroed buffers contiguous at the end -> 1 memset
    float* ws = (float*)d_ws;
    size_t off = 0;
    float* h1    = ws + off; off += (size_t)N_NODES * C1;       // 12.8M
    float* h2    = ws + off; off += (size_t)N_NODES * OUT_DIM;  //  3.2M
    float* as1   = ws + off; off += (size_t)N_NODES * HEADS;
    float* ad1   = ws + off; off += (size_t)N_NODES * HEADS;
    float* wbuf1 = ws + off; off += (size_t)E_TOT * HEADS;
    float* as2   = ws + off; off += N_NODES;
    float* ad2   = ws + off; off += N_NODES;
    float* wbuf2 = ws + off; off += E_TOT;
    float* zstart  = ws + off;
    float* out1agg = ws + off; off += (size_t)N_NODES * C1;
    float* out2agg = ws + off; off += (size_t)N_NODES * OUT_DIM;
    float* den1    = ws + off; off += (size_t)N_NODES * HEADS;
    float* den2    = ws + off; off += N_NODES;
    size_t zbytes = (size_t)((ws + off) - zstart) * sizeof(float);
    hipMemsetAsync(zstart, 0, zbytes, stream);

    gemm1_kernel<<<N_NODES / 16, 256, 0, stream>>>(x, W1, a_src1, a_dst1, h1, as1, ad1);
    edge_pass1_kernel<HEADS><<<(E_TOT + 255) / 256, 256, 0, stream>>>(srcA, dstA, as1, ad1, wbuf1, den1);
    edge_pass2_l1_kernel<<<E_TOT / 4, 256, 0, stream>>>(srcA, dstA, h1, wbuf1, den1, out1agg);
    gemm2_kernel<<<N_NODES / 16, 256, 0, stream>>>(out1agg, b1, W2, a_src2, a_dst2, h2, as2, ad2);
    edge_pass1_kernel<1><<<(E_TOT + 255) / 256, 256, 0, stream>>>(srcA, dstA, as2, ad2, wbuf2, den2);
    edge_pass2_l2_kernel<<<E_TOT / 4, 256, 0, stream>>>(srcA, dstA, h2, wbuf2, den2, out2agg);
    final_kernel<<<(N_NODES * 64) / 256, 256, 0, stream>>>(out2agg, b2, fc_w, fc_b, out);
}

// Round 2
// 607.483 us; speedup vs baseline: 5.6916x; 5.6916x over previous
//
#include <hip/hip_runtime.h>

#define N_NODES 50000
#define N_EDGES 800000
#define E_TOT   850000           // edges + self loops
#define IN_DIM  128
#define HID     64
#define HEADS   4
#define C1      256              // HEADS*HID
#define OUT_DIM 64
#define NEG_SLOPE 0.2f

// ---------------------------------------------------------------------------
// CSR build (by destination): count -> exclusive scan -> fill
// ---------------------------------------------------------------------------
__global__ void count_kernel(const int* __restrict__ dst_a, int* __restrict__ deg)
{
    int j = blockIdx.x * blockDim.x + threadIdx.x;
    if (j >= E_TOT) return;
    int d = (j < N_EDGES) ? dst_a[j] : (j - N_EDGES);   // self loop
    atomicAdd(&deg[d], 1);
}

__global__ __launch_bounds__(1024) void scan_kernel(const int* __restrict__ deg,
                                                    int* __restrict__ rowptr)
{
    __shared__ int psum[1024];
    const int t = threadIdx.x;
    const int CH = (N_NODES + 1023) / 1024;            // 49
    const int base = t * CH;
    int s = 0;
    for (int i = 0; i < CH; i++) {
        int idx = base + i;
        if (idx < N_NODES) s += deg[idx];
    }
    psum[t] = s;
    __syncthreads();
    for (int off = 1; off < 1024; off <<= 1) {         // Hillis-Steele inclusive
        int v = (t >= off) ? psum[t - off] : 0;
        __syncthreads();
        psum[t] += v;
        __syncthreads();
    }
    int run = (t > 0) ? psum[t - 1] : 0;               // exclusive prefix of my chunk
    for (int i = 0; i < CH; i++) {
        int idx = base + i;
        if (idx < N_NODES) { rowptr[idx] = run; run += deg[idx]; }
    }
    if (t == 0) rowptr[N_NODES] = E_TOT;
}

__global__ void fill_kernel(const int* __restrict__ src_a, const int* __restrict__ dst_a,
                            const int* __restrict__ rowptr, int* __restrict__ cursor,
                            int* __restrict__ srcSorted)
{
    int j = blockIdx.x * blockDim.x + threadIdx.x;
    if (j >= E_TOT) return;
    int s, d;
    if (j < N_EDGES) { s = src_a[j]; d = dst_a[j]; }
    else             { s = j - N_EDGES; d = s; }
    int pos = atomicAdd(&cursor[d], 1);
    srcSorted[rowptr[d] + pos] = s;
}

// ---------------------------------------------------------------------------
// GEMM1: h1 = x @ W1  [50000x128]@[128x256], fused per-head projections.
// ---------------------------------------------------------------------------
__global__ __launch_bounds__(256) void gemm1_kernel(
    const float* __restrict__ x, const float* __restrict__ W1,
    const float* __restrict__ a_src1, const float* __restrict__ a_dst1,
    float* __restrict__ h1, float* __restrict__ as1, float* __restrict__ ad1)
{
    __shared__ float xs[16][IN_DIM];           // 8 KiB
    const int t = threadIdx.x;
    const int nodeBase = blockIdx.x * 16;

    {
        const float* src = x + (size_t)nodeBase * IN_DIM;
        float4 v0 = *(const float4*)(src + t * 8);
        float4 v1 = *(const float4*)(src + t * 8 + 4);
        int n = (t * 8) / IN_DIM, k = (t * 8) % IN_DIM;
        *(float4*)&xs[n][k]     = v0;
        *(float4*)&xs[n][k + 4] = v1;
    }
    __syncthreads();

    float acc[16];
    #pragma unroll
    for (int n = 0; n < 16; n++) acc[n] = 0.f;

    for (int k = 0; k < IN_DIM; k += 4) {
        float w0 = W1[(k + 0) * C1 + t];
        float w1 = W1[(k + 1) * C1 + t];
        float w2 = W1[(k + 2) * C1 + t];
        float w3 = W1[(k + 3) * C1 + t];
        #pragma unroll
        for (int n = 0; n < 16; n++) {
            float4 xv = *(const float4*)&xs[n][k];
            acc[n] = fmaf(xv.x, w0, acc[n]);
            acc[n] = fmaf(xv.y, w1, acc[n]);
            acc[n] = fmaf(xv.z, w2, acc[n]);
            acc[n] = fmaf(xv.w, w3, acc[n]);
        }
    }

    #pragma unroll
    for (int n = 0; n < 16; n++)
        h1[(size_t)(nodeBase + n) * C1 + t] = acc[n];

    const int lane = t & 63;
    const int head = t >> 6;
    const float asw = a_src1[t];
    const float adw = a_dst1[t];
    #pragma unroll
    for (int n = 0; n < 16; n++) {
        float s = acc[n] * asw;
        float d = acc[n] * adw;
        #pragma unroll
        for (int off = 32; off; off >>= 1) {
            s += __shfl_down(s, off, 64);
            d += __shfl_down(d, off, 64);
        }
        if (lane == 0) {
            as1[(nodeBase + n) * HEADS + head] = s;
            ad1[(nodeBase + n) * HEADS + head] = d;
        }
    }
}

// ---------------------------------------------------------------------------
// Layer-1 aggregation, gather-style: one wave per dst node, lane = 4 channels.
// Single pass: out[c] = sum_e w_e * h1[src_e][c] / sum_e w_e (no atomics).
// ---------------------------------------------------------------------------
__global__ __launch_bounds__(256) void agg1_kernel(
    const int* __restrict__ rowptr, const int* __restrict__ srcS,
    const float* __restrict__ h1, const float* __restrict__ as1,
    const float* __restrict__ ad1, float* __restrict__ out1agg)
{
    int gid  = blockIdx.x * blockDim.x + threadIdx.x;
    int n    = gid >> 6;
    int lane = threadIdx.x & 63;
    if (n >= N_NODES) return;
    const int h = lane >> 4;                       // head of my 4 channels
    const float adh = ad1[n * HEADS + h];
    const int e0 = rowptr[n], e1 = rowptr[n + 1];

    float4 acc = {0.f, 0.f, 0.f, 0.f};
    float den = 0.f;
    for (int e = e0; e < e1; e++) {
        int s = srcS[e];
        float a = as1[s * HEADS + h] + adh;
        a = a > 0.f ? a : NEG_SLOPE * a;
        float w = __expf(a);
        float4 hv = *(const float4*)(h1 + (size_t)s * C1 + lane * 4);
        acc.x = fmaf(w, hv.x, acc.x);
        acc.y = fmaf(w, hv.y, acc.y);
        acc.z = fmaf(w, hv.z, acc.z);
        acc.w = fmaf(w, hv.w, acc.w);
        den += w;
    }
    float inv = 1.f / (den + 1e-16f);
    float4 o = {acc.x * inv, acc.y * inv, acc.z * inv, acc.w * inv};
    *(float4*)(out1agg + (size_t)n * C1 + lane * 4) = o;
}

// ---------------------------------------------------------------------------
// GEMM2: h2 = ELU(out1agg + b1) @ W2, fused as2/ad2 projections.
// ---------------------------------------------------------------------------
__global__ __launch_bounds__(256) void gemm2_kernel(
    const float* __restrict__ in_agg, const float* __restrict__ b1,
    const float* __restrict__ W2, const float* __restrict__ a_src2,
    const float* __restrict__ a_dst2,
    float* __restrict__ h2, float* __restrict__ as2, float* __restrict__ ad2)
{
    __shared__ float xs[16][C1];               // 16 KiB
    const int t = threadIdx.x;
    const int nodeBase = blockIdx.x * 16;

    {
        const float* src = in_agg + (size_t)nodeBase * C1;
        #pragma unroll
        for (int i = 0; i < 4; i++) {
            int idx = t * 16 + i * 4;
            int n = idx / C1, c = idx % C1;
            float4 v  = *(const float4*)(src + idx);
            float4 bb = *(const float4*)(b1 + c);
            v.x += bb.x; v.y += bb.y; v.z += bb.z; v.w += bb.w;
            v.x = v.x > 0.f ? v.x : __expf(v.x) - 1.f;
            v.y = v.y > 0.f ? v.y : __expf(v.y) - 1.f;
            v.z = v.z > 0.f ? v.z : __expf(v.z) - 1.f;
            v.w = v.w > 0.f ? v.w : __expf(v.w) - 1.f;
            *(float4*)&xs[n][c] = v;
        }
    }
    __syncthreads();

    const int c = t & 63;
    const int sub = t >> 6;
    float acc[4];
    #pragma unroll
    for (int i = 0; i < 4; i++) acc[i] = 0.f;

    for (int k = 0; k < C1; k += 4) {
        float w0 = W2[(k + 0) * OUT_DIM + c];
        float w1 = W2[(k + 1) * OUT_DIM + c];
        float w2v = W2[(k + 2) * OUT_DIM + c];
        float w3 = W2[(k + 3) * OUT_DIM + c];
        #pragma unroll
        for (int i = 0; i < 4; i++) {
            float4 xv = *(const float4*)&xs[sub * 4 + i][k];
            acc[i] = fmaf(xv.x, w0, acc[i]);
            acc[i] = fmaf(xv.y, w1, acc[i]);
            acc[i] = fmaf(xv.z, w2v, acc[i]);
            acc[i] = fmaf(xv.w, w3, acc[i]);
        }
    }

    const float asw = a_src2[c];
    const float adw = a_dst2[c];
    #pragma unroll
    for (int i = 0; i < 4; i++) {
        int node = nodeBase + sub * 4 + i;
        h2[(size_t)node * OUT_DIM + c] = acc[i];
        float s = acc[i] * asw;
        float dd = acc[i] * adw;
        #pragma unroll
        for (int off = 32; off; off >>= 1) {
            s  += __shfl_down(s, off, 64);
            dd += __shfl_down(dd, off, 64);
        }
        if (c == 0) { as2[node] = s; ad2[node] = dd; }
    }
}

// ---------------------------------------------------------------------------
// Layer-2 aggregation + bias + fc dot, fused: one wave per dst node,
// lane = channel (OUT_DIM=64). Writes final scalar out[n]. No atomics.
// ---------------------------------------------------------------------------
__global__ __launch_bounds__(256) void agg2_final_kernel(
    const int* __restrict__ rowptr, const int* __restrict__ srcS,
    const float* __restrict__ h2, const float* __restrict__ as2,
    const float* __restrict__ ad2, const float* __restrict__ b2,
    const float* __restrict__ fc_w, const float* __restrict__ fc_b,
    float* __restrict__ out)
{
    int gid  = blockIdx.x * blockDim.x + threadIdx.x;
    int n    = gid >> 6;
    int lane = threadIdx.x & 63;
    if (n >= N_NODES) return;
    const float adh = ad2[n];
    const int e0 = rowptr[n], e1 = rowptr[n + 1];

    float acc = 0.f, den = 0.f;
    for (int e = e0; e < e1; e++) {
        int s = srcS[e];
        float a = as2[s] + adh;                    // broadcast scalar load
        a = a > 0.f ? a : NEG_SLOPE * a;
        float w = __expf(a);
        acc = fmaf(w, h2[(size_t)s * OUT_DIM + lane], acc);
        den += w;
    }
    float v = acc / (den + 1e-16f) + b2[lane];
    float r = v * fc_w[lane];
    #pragma unroll
    for (int off = 32; off; off >>= 1) r += __shfl_down(r, off, 64);
    if (lane == 0) out[n] = r + fc_b[0];
}

extern "C" void kernel_launch(void* const* d_in, const int* in_sizes, int n_in,
                              void* d_out, int out_size, void* d_ws, size_t ws_size,
                              hipStream_t stream)
{
    const float* x      = (const float*)d_in[0];
    const int*   ei     = (const int*)d_in[1];
    const float* W1     = (const float*)d_in[2];
    const float* a_src1 = (const float*)d_in[3];
    const float* a_dst1 = (const float*)d_in[4];
    const float* b1     = (const float*)d_in[5];
    const float* W2     = (const float*)d_in[6];
    const float* a_src2 = (const float*)d_in[7];
    const float* a_dst2 = (const float*)d_in[8];
    const float* b2     = (const float*)d_in[9];
    const float* fc_w   = (const float*)d_in[10];
    const float* fc_b   = (const float*)d_in[11];
    float* out = (float*)d_out;

    const int* srcA = ei;
    const int* dstA = ei + N_EDGES;

    // workspace layout
    float* ws = (float*)d_ws;
    size_t off = 0;
    float* h1      = ws + off; off += (size_t)N_NODES * C1;       // 12.8M
    float* out1agg = ws + off; off += (size_t)N_NODES * C1;       // 12.8M
    float* h2      = ws + off; off += (size_t)N_NODES * OUT_DIM;  //  3.2M
    float* as1     = ws + off; off += (size_t)N_NODES * HEADS;
    float* ad1     = ws + off; off += (size_t)N_NODES * HEADS;
    float* as2     = ws + off; off += N_NODES;
    float* ad2     = ws + off; off += N_NODES;
    int* rowptr    = (int*)(ws + off); off += N_NODES + 1 + 1;    // 50001 (+pad)
    int* srcSorted = (int*)(ws + off); off += E_TOT;
    int* zstart    = (int*)(ws + off);
    int* deg       = (int*)(ws + off); off += N_NODES;
    int* cursor    = (int*)(ws + off); off += N_NODES;
    hipMemsetAsync(zstart, 0, 2 * N_NODES * sizeof(int), stream);

    // CSR build
    count_kernel<<<(E_TOT + 255) / 256, 256, 0, stream>>>(dstA, deg);
    scan_kernel<<<1, 1024, 0, stream>>>(deg, rowptr);
    fill_kernel<<<(E_TOT + 255) / 256, 256, 0, stream>>>(srcA, dstA, rowptr, cursor, srcSorted);

    // layer 1
    gemm1_kernel<<<N_NODES / 16, 256, 0, stream>>>(x, W1, a_src1, a_dst1, h1, as1, ad1);
    agg1_kernel<<<(N_NODES * 64 + 255) / 256, 256, 0, stream>>>(rowptr, srcSorted, h1, as1, ad1, out1agg);

    // layer 2 + final
    gemm2_kernel<<<N_NODES / 16, 256, 0, stream>>>(out1agg, b1, W2, a_src2, a_dst2, h2, as2, ad2);
    agg2_final_kernel<<<(N_NODES * 64 + 255) / 256, 256, 0, stream>>>(rowptr, srcSorted, h2, as2, ad2, b2, fc_w, fc_b, out);
}